// Round 1
// baseline (346.267 us; speedup 1.0000x reference)
//
#include <hip/hip_runtime.h>
#include <stdint.h>

typedef _Float16 half8  __attribute__((ext_vector_type(8)));
typedef _Float16 half4v __attribute__((ext_vector_type(4)));
typedef float    floatx4 __attribute__((ext_vector_type(4)));

#define LOG2E 1.44269504088896340736f

// async global->LDS 16B copy (LDS dest must be wave-uniform base + lane*16)
__device__ __forceinline__ void gl_lds16(const _Float16* g, _Float16* l) {
  __builtin_amdgcn_global_load_lds(
      (__attribute__((address_space(1))) void*)g,
      (__attribute__((address_space(3))) void*)l, 16, 0, 0);
}
__device__ __forceinline__ void gl_lds16f(const float* g, float* l) {
  __builtin_amdgcn_global_load_lds(
      (__attribute__((address_space(1))) void*)g,
      (__attribute__((address_space(3))) void*)l, 16, 0, 0);
}

__device__ __forceinline__ half4v pack4(float a, float b, float c, float d) {
  auto lo = __builtin_amdgcn_cvt_pkrtz(a, b);
  auto hi = __builtin_amdgcn_cvt_pkrtz(c, d);
  return half4v{static_cast<_Float16>(lo[0]), static_cast<_Float16>(lo[1]),
                static_cast<_Float16>(hi[0]), static_cast<_Float16>(hi[1])};
}
__device__ __forceinline__ half8 cvt8(floatx4 a, floatx4 b) {
  half4v lo = pack4(a[0], a[1], a[2], a[3]);
  half4v hi = pack4(b[0], b[1], b[2], b[3]);
  return __builtin_shufflevector(lo, hi, 0, 1, 2, 3, 4, 5, 6, 7);
}

// ---------------- kernel 1: fp32 -> f16 convert (weights only) ----------------
struct CvtArgs {
  const float* src[3];
  _Float16*    dst[3];
};

__global__ void cvt_kernel(CvtArgs a) {
  const int z = blockIdx.y;
  const int i = (blockIdx.x * 256 + threadIdx.x) * 8;
  const float4* s = (const float4*)(a.src[z] + i);
  float4 v0 = s[0], v1 = s[1];
  half8 h = { (_Float16)v0.x, (_Float16)v0.y, (_Float16)v0.z, (_Float16)v0.w,
              (_Float16)v1.x, (_Float16)v1.y, (_Float16)v1.z, (_Float16)v1.w };
  *(half8*)(a.dst[z] + i) = h;
}

// ---------------- kernel 2: QKV projection GEMM (unchanged this round) -------
__device__ __forceinline__ void gemm_stage(const float* __restrict__ X,
                                           const _Float16* __restrict__ W,
                                           float* Asb, _Float16* Bsb,
                                           int m0, int n0, int k0, int tid) {
  #pragma unroll
  for (int i = 0; i < 4; ++i) {          // A: 128 rows x 32 fp32 = 16KB
    int G = i * 256 + tid;
    int r = G >> 3, gl = G & 7;
    int g = gl ^ (r & 7);
    gl_lds16f(X + (size_t)(m0 + r) * 768 + k0 + g * 4, Asb + G * 4);
  }
  #pragma unroll
  for (int i = 0; i < 2; ++i) {          // B: 128 rows x 32 f16 = 8KB
    int G = i * 256 + tid;
    int r = G >> 2, gl = G & 3;
    int g = gl ^ ((r >> 1) & 3);
    gl_lds16(W + (size_t)(n0 + r) * 768 + k0 + g * 8, Bsb + G * 8);
  }
}

template <int BUF>
__device__ __forceinline__ void gemm_body(
    int knext, const float* __restrict__ X, const _Float16* __restrict__ W,
    float* As, _Float16* Bs, int m0, int n0, int tid, int z,
    int wr, int wc, int qd, int col, floatx4 (&acc)[4][4])
{
  if (knext < 768)
    gemm_stage(X, W, As + (1 - BUF) * 4096, Bs + (1 - BUF) * 4096, m0, n0, knext, tid);

  half8 af[4], bf[4];
  #pragma unroll
  for (int t = 0; t < 4; ++t) {
    int ra = wr * 64 + t * 16 + col;
    const float* Ab = As + BUF * 4096 + ra * 32;
    floatx4 a0 = *(const floatx4*)(Ab + (((2 * qd)     ^ (ra & 7)) * 4));
    floatx4 a1 = *(const floatx4*)(Ab + (((2 * qd + 1) ^ (ra & 7)) * 4));
    af[t] = cvt8(a0, a1);
  }
  #pragma unroll
  for (int t = 0; t < 4; ++t) {
    int rb = wc * 64 + t * 16 + col;
    bf[t] = *(const half8*)(Bs + BUF * 4096 + rb * 32 + ((qd ^ ((rb >> 1) & 3)) * 8));
  }
  if (z == 2) {
    #pragma unroll
    for (int i = 0; i < 4; ++i)
      #pragma unroll
      for (int j = 0; j < 4; ++j)
        acc[i][j] = __builtin_amdgcn_mfma_f32_16x16x32_f16(af[i], bf[j], acc[i][j], 0, 0, 0);
  } else {
    #pragma unroll
    for (int i = 0; i < 4; ++i)
      #pragma unroll
      for (int j = 0; j < 4; ++j)
        acc[i][j] = __builtin_amdgcn_mfma_f32_16x16x32_f16(bf[j], af[i], acc[i][j], 0, 0, 0);
  }
  __syncthreads();
}

__global__ __launch_bounds__(256, 2) void qkv_gemm(
    const float* __restrict__ qx, const float* __restrict__ kx, const float* __restrict__ vx,
    const _Float16* __restrict__ wh,
    const float* __restrict__ bqp, const float* __restrict__ bkp, const float* __restrict__ bvp,
    _Float16* __restrict__ oq, _Float16* __restrict__ ok, _Float16* __restrict__ ovt)
{
  __shared__ __attribute__((aligned(16))) char smem[49152];
  float*    As = (float*)smem;                    // 2*4096 fp32 = 32 KB
  _Float16* Bs = (_Float16*)(smem + 32768);       // 2*4096 f16  = 16 KB
  _Float16* Es = (_Float16*)smem;                 // epilogue 128 rows x 160 halfs = 40 KB

  const int z  = blockIdx.z;
  const float* X = (z == 0) ? qx : ((z == 1) ? kx : vx);
  const _Float16* W = wh + (size_t)z * 589824;
  const int m0 = blockIdx.x * 128, n0 = blockIdx.y * 128;
  const int tid  = threadIdx.x;
  const int lane = tid & 63, wid = tid >> 6;
  const int wr = wid >> 1, wc = wid & 1;
  const int qd = lane >> 4, col = lane & 15;

  const floatx4 z4 = {0.f, 0.f, 0.f, 0.f};
  floatx4 acc[4][4];
  #pragma unroll
  for (int i = 0; i < 4; ++i)
    #pragma unroll
    for (int j = 0; j < 4; ++j) acc[i][j] = z4;

  gemm_stage(X, W, As, Bs, m0, n0, 0, tid);
  __syncthreads();
  for (int kk = 0; kk < 768; kk += 64) {
    gemm_body<0>(kk + 32, X, W, As, Bs, m0, n0, tid, z, wr, wc, qd, col, acc);
    gemm_body<1>(kk + 64, X, W, As, Bs, m0, n0, tid, z, wr, wc, qd, col, acc);
  }
  // last gemm_body ended with __syncthreads: As/Bs dead, Es reusable

  const float* bias = (z == 0) ? bqp : ((z == 1) ? bkp : bvp);
  const int b = m0 >> 11, s0 = m0 & 2047;   // 128-row tile never crosses a batch
  if (z == 2) {
    #pragma unroll
    for (int j = 0; j < 4; ++j) {
      int n_loc = wc * 64 + j * 16 + col;
      float bb = bias[n0 + n_loc];
      #pragma unroll
      for (int i = 0; i < 4; ++i) {
        int s_loc = wr * 64 + i * 16 + qd * 4;
        half4v h = pack4(acc[i][j][0] + bb, acc[i][j][1] + bb,
                         acc[i][j][2] + bb, acc[i][j][3] + bb);
        *(half4v*)(Es + n_loc * 160 + s_loc) = h;
      }
    }
    __syncthreads();
    #pragma unroll
    for (int it = 0; it < 8; ++it) {
      int row = it * 16 + (tid >> 4);
      int k   = tid & 15;
      half8 vr = *(const half8*)(Es + row * 160 + k * 8);
      *(half8*)(ovt + ((size_t)(b * 768 + n0 + row)) * 2048 + s0 + k * 8) = vr;
    }
  } else {
    _Float16* O = (z == 0) ? oq : ok;
    const float scale = (z == 0) ? LOG2E : 1.0f;
    #pragma unroll
    for (int j = 0; j < 4; ++j) {
      int n_loc = wc * 64 + j * 16 + qd * 4;
      float4 bb = *(const float4*)(bias + n0 + n_loc);
      #pragma unroll
      for (int i = 0; i < 4; ++i) {
        int s_loc = wr * 64 + i * 16 + col;
        half4v h = pack4((acc[i][j][0] + bb.x) * scale, (acc[i][j][1] + bb.y) * scale,
                         (acc[i][j][2] + bb.z) * scale, (acc[i][j][3] + bb.w) * scale);
        *(half4v*)(Es + s_loc * 160 + n_loc) = h;
      }
    }
    __syncthreads();
    const int hh0 = n0 >> 6;
    #pragma unroll
    for (int it = 0; it < 8; ++it) {
      int seg = it * 32 + (tid >> 3);
      int s = seg >> 1, hseg = seg & 1;
      int k = tid & 7;
      half8 vr = *(const half8*)(Es + s * 160 + hseg * 64 + k * 8);
      int mb = (m0 + s) >> 11, sg = (m0 + s) & 2047;
      *(half8*)(O + (size_t)(mb * 12 + hh0 + hseg) * 131072
                  + (size_t)sg * 64 + k * 8) = vr;
    }
  }
}

// ---------------- kernel 3: flash attention (qt=4 rewrite) -----------------
// r0 diagnosis: DS pipe ~saturated (12 waves x 256B/lane/body) + 6.29M LDS
// bank-conflict cycles = exactly 64/wave-body, traced to the V b64 reads
// (col and col+8 share a bank pair within each 16-lane phase).
// This version:
//  - 2 waves/block (128 thr), 64 q-rows/wave (qt=0..3), grid (48,16)=768:
//    K/V LDS bytes per wave-body unchanged but FLOP doubled -> DS/FLOP halved.
//  - V reg-staged (global->reg->2x ds_write_b64) with half-slot swizzle
//    h' = h ^ ((d>>3)&1) ^ (d&1) on top of the granule XOR: all 16-lane
//    phases of V reads AND V writes hit 16 distinct bank pairs (conflict-free).
//  - K stays on global_load_lds (layout already conflict-free).
//  - exp2 fast path: when __all(tile_max <= 0) skip the "-mr" subtract.
//  - staging addresses are incremented pointers, not rebuilt per body.

template <int BUF>
__device__ __forceinline__ void attn_body(
    bool pref, const _Float16*& kp, const _Float16*& vp,
    _Float16* Ks, char* Vs, int tid, int vwA, int vwB,
    const half8 (&qf)[4][2], int kb0, int kb1, const int (&vb)[4],
    float (&nm)[4], floatx4 (&ol)[4], floatx4 (&o)[4][4])
{
  int4 vr[4];
  if (pref) {
    _Float16* ksd = Ks + (1 - BUF) * 4096;
    #pragma unroll
    for (int i = 0; i < 4; ++i)
      gl_lds16(kp + i * 1024, ksd + (i * 128 + tid) * 8);
    #pragma unroll
    for (int i = 0; i < 4; ++i)
      vr[i] = *(const int4*)(vp + (size_t)i * 32768);
    kp += 4096;   // next 64 j rows of K
    vp += 64;     // next 64 j cols of V^T
  }

  const char* ksb = (const char*)Ks + BUF * 8192;
  const char* vsb = Vs + BUF * 8192;

  half8 kf0[4], kf1[4];
  #pragma unroll
  for (int t = 0; t < 4; ++t) {
    kf0[t] = *(const half8*)(ksb + t * 2048 + kb0);
    kf1[t] = *(const half8*)(ksb + t * 2048 + kb1);
  }

  // QK^T + online softmax, 4 independent q-tiles per wave
  half4v pf[4][4];
  #pragma unroll
  for (int qt = 0; qt < 4; ++qt) {
    floatx4 seed = {nm[qt], nm[qt], nm[qt], nm[qt]};
    floatx4 st[4];
    #pragma unroll
    for (int t = 0; t < 4; ++t) {
      st[t] = __builtin_amdgcn_mfma_f32_16x16x32_f16(kf0[t], qf[qt][0], seed, 0, 0, 0);
      st[t] = __builtin_amdgcn_mfma_f32_16x16x32_f16(kf1[t], qf[qt][1], st[t], 0, 0, 0);
    }
    float v = fmaxf(
        fmaxf(fmaxf(fmaxf(st[0][0], st[0][1]), fmaxf(st[0][2], st[0][3])),
              fmaxf(fmaxf(st[1][0], st[1][1]), fmaxf(st[1][2], st[1][3]))),
        fmaxf(fmaxf(fmaxf(st[2][0], st[2][1]), fmaxf(st[2][2], st[2][3])),
              fmaxf(fmaxf(st[3][0], st[3][1]), fmaxf(st[3][2], st[3][3]))));
    v = fmaxf(v, __shfl_xor(v, 16, 64));
    v = fmaxf(v, __shfl_xor(v, 32, 64));
    if (__any(v > 0.f)) {            // rare: running max must move
      float mr = fmaxf(v, 0.f);
      float al = __builtin_amdgcn_exp2f(-mr);
      nm[qt] -= mr;
      ol[qt] *= al;
      #pragma unroll
      for (int dt = 0; dt < 4; ++dt) o[dt][qt] *= al;
      #pragma unroll
      for (int t = 0; t < 4; ++t)
        pf[t][qt] = pack4(__builtin_amdgcn_exp2f(st[t][0] - mr),
                          __builtin_amdgcn_exp2f(st[t][1] - mr),
                          __builtin_amdgcn_exp2f(st[t][2] - mr),
                          __builtin_amdgcn_exp2f(st[t][3] - mr));
    } else {                         // common: st <= 0 already
      #pragma unroll
      for (int t = 0; t < 4; ++t)
        pf[t][qt] = pack4(__builtin_amdgcn_exp2f(st[t][0]),
                          __builtin_amdgcn_exp2f(st[t][1]),
                          __builtin_amdgcn_exp2f(st[t][2]),
                          __builtin_amdgcn_exp2f(st[t][3]));
    }
  }

  // V staging writes (loads issued at body top have had the QK phase to land)
  if (pref) {
    char* vsd = Vs + (1 - BUF) * 8192;
    #pragma unroll
    for (int i = 0; i < 4; ++i) {
      int2 lo; lo.x = vr[i].x; lo.y = vr[i].y;
      int2 hi; hi.x = vr[i].z; hi.y = vr[i].w;
      *(int2*)(vsd + vwA + i * 2048) = lo;
      *(int2*)(vsd + vwB + i * 2048) = hi;
    }
  }

  // PV: out^T = V^T . P (K=16, P straight from regs); ones-row MFMA carries l
  const half4v vone = {(_Float16)1.0f, (_Float16)1.0f, (_Float16)1.0f, (_Float16)1.0f};
  #pragma unroll
  for (int dt = 0; dt < 4; ++dt) {
    #pragma unroll
    for (int t = 0; t < 4; ++t) {
      half4v vf = *(const half4v*)(vsb + dt * 2048 + vb[t]);
      #pragma unroll
      for (int qt = 0; qt < 4; ++qt)
        o[dt][qt] = __builtin_amdgcn_mfma_f32_16x16x16f16(vf, pf[t][qt], o[dt][qt], 0, 0, 0);
    }
  }
  #pragma unroll
  for (int t = 0; t < 4; ++t)
    #pragma unroll
    for (int qt = 0; qt < 4; ++qt)
      ol[qt] = __builtin_amdgcn_mfma_f32_16x16x16f16(vone, pf[t][qt], ol[qt], 0, 0, 0);

  __syncthreads();
}

__global__ __launch_bounds__(128, 2) void attn_kernel(
    const _Float16* __restrict__ Qm,   // [48][2048][64] (log2e-scaled)
    const _Float16* __restrict__ Km,   // [48][2048][64]
    const _Float16* __restrict__ Vt,   // [48][64][2048]
    float* __restrict__ out)           // [4][2048][768]
{
  __shared__ __attribute__((aligned(16))) _Float16 Ks[2 * 4096];  // 16 KB
  __shared__ __attribute__((aligned(16))) char     Vs[2 * 8192];  // 16 KB
  const int bh = blockIdx.x;                 // XCD = bh % 8 (48 % 8 == 0)
  const int q0 = blockIdx.y * 128;
  const int tid = threadIdx.x, lane = tid & 63, w = tid >> 6;
  const int qd = lane >> 4, col = lane & 15, c7 = col & 7;
  const _Float16* Qg = Qm + (size_t)bh * 131072;
  const _Float16* Kg = Km + (size_t)bh * 131072;
  const _Float16* Vg = Vt + (size_t)bh * 131072;

  // Q fragments direct from global (kept in regs for the whole kernel)
  half8 qf[4][2];
  #pragma unroll
  for (int qt = 0; qt < 4; ++qt)
    #pragma unroll
    for (int ks = 0; ks < 2; ++ks)
      qf[qt][ks] = *(const half8*)(Qg + (size_t)(q0 + w * 64 + qt * 16 + col) * 64
                                   + (ks * 4 + qd) * 8);

  // loop-invariant per-lane LDS byte offsets
  const int kb0 = col * 128 + ((qd ^ c7) * 16);
  const int kb1 = col * 128 + (((4 + qd) ^ c7) * 16);
  const int rsz = ((col >> 3) ^ col) & 1;              // read-side half-slot xor
  int vb[4];
  #pragma unroll
  for (int t = 0; t < 4; ++t)
    vb[t] = col * 128 + ((((2 * t) | (qd >> 1)) ^ c7) * 16) + (((qd & 1) ^ rsz) * 8);

  // staging geometry (constant per thread)
  const int r0 = tid >> 3, scg = tid & 7;              // 16 rows x 8 granules
  const int gsw = scg ^ (r0 & 7);
  const int wsz = ((r0 >> 3) ^ r0) & 1;                // write-side half-slot xor
  const int vwA = r0 * 128 + gsw * 16 + wsz * 8;       // lo half dest
  const int vwB = r0 * 128 + gsw * 16 + (wsz ^ 1) * 8; // hi half dest
  const _Float16* kp = Kg + r0 * 64 + gsw * 8;         // pre-swizzled K source
  const _Float16* vp = Vg + (size_t)r0 * 2048 + scg * 8;

  float nm[4] = {100.f, 100.f, 100.f, 100.f};  // forces first-tile rescale
  const floatx4 z4 = {0.f, 0.f, 0.f, 0.f};
  floatx4 ol[4] = {z4, z4, z4, z4};
  floatx4 o[4][4];
  #pragma unroll
  for (int dt = 0; dt < 4; ++dt)
    #pragma unroll
    for (int qt = 0; qt < 4; ++qt) o[dt][qt] = z4;

  // prologue: stage tile 0 into buf 0
  {
    #pragma unroll
    for (int i = 0; i < 4; ++i)
      gl_lds16(kp + i * 1024, Ks + (i * 128 + tid) * 8);
    int4 v0[4];
    #pragma unroll
    for (int i = 0; i < 4; ++i) v0[i] = *(const int4*)(vp + (size_t)i * 32768);
    kp += 4096; vp += 64;
    #pragma unroll
    for (int i = 0; i < 4; ++i) {
      int2 lo; lo.x = v0[i].x; lo.y = v0[i].y;
      int2 hi; hi.x = v0[i].z; hi.y = v0[i].w;
      *(int2*)(Vs + vwA + i * 2048) = lo;
      *(int2*)(Vs + vwB + i * 2048) = hi;
    }
  }
  __syncthreads();

  for (int jj = 0; jj < 2048; jj += 128) {
    attn_body<0>(true,              kp, vp, Ks, Vs, tid, vwA, vwB, qf, kb0, kb1, vb, nm, ol, o);
    attn_body<1>(jj + 128 < 2048,   kp, vp, Ks, Vs, tid, vwA, vwB, qf, kb0, kb1, vb, nm, ol, o);
  }

  // epilogue: l from the ones-MFMA accumulator (all 4 regs equal, col=q)
  const int b = bh / 12, h = bh % 12;
  #pragma unroll
  for (int qt = 0; qt < 4; ++qt) {
    float inv = 1.0f / ol[qt][0];
    int qg = q0 + w * 64 + qt * 16 + col;
    float* obase = out + ((size_t)b * 2048 + qg) * 768 + h * 64;
    #pragma unroll
    for (int dt = 0; dt < 4; ++dt) {
      floatx4 v = o[dt][qt];
      v *= inv;
      *(floatx4*)(obase + dt * 16 + qd * 4) = v;
    }
  }
}

// ---------------- launcher ----------------
extern "C" void kernel_launch(void* const* d_in, const int* in_sizes, int n_in,
                              void* d_out, int out_size, void* d_ws, size_t ws_size,
                              hipStream_t stream) {
  const float* q  = (const float*)d_in[0];
  const float* k  = (const float*)d_in[1];
  const float* v  = (const float*)d_in[2];
  const float* Wq = (const float*)d_in[3];
  const float* bq = (const float*)d_in[4];
  const float* Wk = (const float*)d_in[5];
  const float* bk = (const float*)d_in[6];
  const float* Wv = (const float*)d_in[7];
  const float* bv = (const float*)d_in[8];

  const size_t NX = 6291456;   // 4*2048*768
  const size_t NW = 589824;    // 768*768
  const size_t need = (3 * NW + 3 * NX) * sizeof(_Float16);
  if (ws_size < need) return;

  _Float16* wh = (_Float16*)d_ws;            // [3][768][768] f16 weights
  _Float16* qh = wh + 3 * NW;                // Q' [48][2048][64] (log2e-scaled)
  _Float16* kh = qh + NX;                    // K' [48][2048][64]
  _Float16* vt = kh + NX;                    // V'^T [48][64][2048]

  CvtArgs ca;
  ca.src[0] = Wq; ca.src[1] = Wk; ca.src[2] = Wv;
  ca.dst[0] = wh; ca.dst[1] = wh + NW; ca.dst[2] = wh + 2 * NW;

  cvt_kernel<<<dim3(288, 3), 256, 0, stream>>>(ca);
  qkv_gemm<<<dim3(64, 6, 3), 256, 0, stream>>>(q, k, v, wh, bq, bk, bv, qh, kh, vt);
  attn_kernel<<<dim3(48, 16), 128, 0, stream>>>(qh, kh, vt, (float*)d_out);
}

// Round 2
// 258.452 us; speedup vs baseline: 1.3398x; 1.3398x over previous
//
#include <hip/hip_runtime.h>
#include <stdint.h>

typedef _Float16 half8  __attribute__((ext_vector_type(8)));
typedef _Float16 half4v __attribute__((ext_vector_type(4)));
typedef float    floatx4 __attribute__((ext_vector_type(4)));

#define LOG2E 1.44269504088896340736f

// async global->LDS 16B copy (LDS dest must be wave-uniform base + lane*16)
__device__ __forceinline__ void gl_lds16(const _Float16* g, _Float16* l) {
  __builtin_amdgcn_global_load_lds(
      (__attribute__((address_space(1))) void*)g,
      (__attribute__((address_space(3))) void*)l, 16, 0, 0);
}
__device__ __forceinline__ void gl_lds16f(const float* g, float* l) {
  __builtin_amdgcn_global_load_lds(
      (__attribute__((address_space(1))) void*)g,
      (__attribute__((address_space(3))) void*)l, 16, 0, 0);
}

__device__ __forceinline__ half4v pack4(float a, float b, float c, float d) {
  auto lo = __builtin_amdgcn_cvt_pkrtz(a, b);
  auto hi = __builtin_amdgcn_cvt_pkrtz(c, d);
  return half4v{static_cast<_Float16>(lo[0]), static_cast<_Float16>(lo[1]),
                static_cast<_Float16>(hi[0]), static_cast<_Float16>(hi[1])};
}
__device__ __forceinline__ half8 cvt8(floatx4 a, floatx4 b) {
  half4v lo = pack4(a[0], a[1], a[2], a[3]);
  half4v hi = pack4(b[0], b[1], b[2], b[3]);
  return __builtin_shufflevector(lo, hi, 0, 1, 2, 3, 4, 5, 6, 7);
}

// ---------------- kernel 1: fp32 -> f16 convert (weights only) ----------------
struct CvtArgs {
  const float* src[3];
  _Float16*    dst[3];
};

__global__ void cvt_kernel(CvtArgs a) {
  const int z = blockIdx.y;
  const int i = (blockIdx.x * 256 + threadIdx.x) * 8;
  const float4* s = (const float4*)(a.src[z] + i);
  float4 v0 = s[0], v1 = s[1];
  half8 h = { (_Float16)v0.x, (_Float16)v0.y, (_Float16)v0.z, (_Float16)v0.w,
              (_Float16)v1.x, (_Float16)v1.y, (_Float16)v1.z, (_Float16)v1.w };
  *(half8*)(a.dst[z] + i) = h;
}

// ---------------- kernel 2: QKV projection GEMM (unchanged this round) -------
__device__ __forceinline__ void gemm_stage(const float* __restrict__ X,
                                           const _Float16* __restrict__ W,
                                           float* Asb, _Float16* Bsb,
                                           int m0, int n0, int k0, int tid) {
  #pragma unroll
  for (int i = 0; i < 4; ++i) {          // A: 128 rows x 32 fp32 = 16KB
    int G = i * 256 + tid;
    int r = G >> 3, gl = G & 7;
    int g = gl ^ (r & 7);
    gl_lds16f(X + (size_t)(m0 + r) * 768 + k0 + g * 4, Asb + G * 4);
  }
  #pragma unroll
  for (int i = 0; i < 2; ++i) {          // B: 128 rows x 32 f16 = 8KB
    int G = i * 256 + tid;
    int r = G >> 2, gl = G & 3;
    int g = gl ^ ((r >> 1) & 3);
    gl_lds16(W + (size_t)(n0 + r) * 768 + k0 + g * 8, Bsb + G * 8);
  }
}

template <int BUF>
__device__ __forceinline__ void gemm_body(
    int knext, const float* __restrict__ X, const _Float16* __restrict__ W,
    float* As, _Float16* Bs, int m0, int n0, int tid, int z,
    int wr, int wc, int qd, int col, floatx4 (&acc)[4][4])
{
  if (knext < 768)
    gemm_stage(X, W, As + (1 - BUF) * 4096, Bs + (1 - BUF) * 4096, m0, n0, knext, tid);

  half8 af[4], bf[4];
  #pragma unroll
  for (int t = 0; t < 4; ++t) {
    int ra = wr * 64 + t * 16 + col;
    const float* Ab = As + BUF * 4096 + ra * 32;
    floatx4 a0 = *(const floatx4*)(Ab + (((2 * qd)     ^ (ra & 7)) * 4));
    floatx4 a1 = *(const floatx4*)(Ab + (((2 * qd + 1) ^ (ra & 7)) * 4));
    af[t] = cvt8(a0, a1);
  }
  #pragma unroll
  for (int t = 0; t < 4; ++t) {
    int rb = wc * 64 + t * 16 + col;
    bf[t] = *(const half8*)(Bs + BUF * 4096 + rb * 32 + ((qd ^ ((rb >> 1) & 3)) * 8));
  }
  if (z == 2) {
    #pragma unroll
    for (int i = 0; i < 4; ++i)
      #pragma unroll
      for (int j = 0; j < 4; ++j)
        acc[i][j] = __builtin_amdgcn_mfma_f32_16x16x32_f16(af[i], bf[j], acc[i][j], 0, 0, 0);
  } else {
    #pragma unroll
    for (int i = 0; i < 4; ++i)
      #pragma unroll
      for (int j = 0; j < 4; ++j)
        acc[i][j] = __builtin_amdgcn_mfma_f32_16x16x32_f16(bf[j], af[i], acc[i][j], 0, 0, 0);
  }
  __syncthreads();
}

__global__ __launch_bounds__(256, 2) void qkv_gemm(
    const float* __restrict__ qx, const float* __restrict__ kx, const float* __restrict__ vx,
    const _Float16* __restrict__ wh,
    const float* __restrict__ bqp, const float* __restrict__ bkp, const float* __restrict__ bvp,
    _Float16* __restrict__ oq, _Float16* __restrict__ ok, _Float16* __restrict__ ovt)
{
  __shared__ __attribute__((aligned(16))) char smem[49152];
  float*    As = (float*)smem;                    // 2*4096 fp32 = 32 KB
  _Float16* Bs = (_Float16*)(smem + 32768);       // 2*4096 f16  = 16 KB
  _Float16* Es = (_Float16*)smem;                 // epilogue 128 rows x 160 halfs = 40 KB

  const int z  = blockIdx.z;
  const float* X = (z == 0) ? qx : ((z == 1) ? kx : vx);
  const _Float16* W = wh + (size_t)z * 589824;
  const int m0 = blockIdx.x * 128, n0 = blockIdx.y * 128;
  const int tid  = threadIdx.x;
  const int lane = tid & 63, wid = tid >> 6;
  const int wr = wid >> 1, wc = wid & 1;
  const int qd = lane >> 4, col = lane & 15;

  const floatx4 z4 = {0.f, 0.f, 0.f, 0.f};
  floatx4 acc[4][4];
  #pragma unroll
  for (int i = 0; i < 4; ++i)
    #pragma unroll
    for (int j = 0; j < 4; ++j) acc[i][j] = z4;

  gemm_stage(X, W, As, Bs, m0, n0, 0, tid);
  __syncthreads();
  for (int kk = 0; kk < 768; kk += 64) {
    gemm_body<0>(kk + 32, X, W, As, Bs, m0, n0, tid, z, wr, wc, qd, col, acc);
    gemm_body<1>(kk + 64, X, W, As, Bs, m0, n0, tid, z, wr, wc, qd, col, acc);
  }
  // last gemm_body ended with __syncthreads: As/Bs dead, Es reusable

  const float* bias = (z == 0) ? bqp : ((z == 1) ? bkp : bvp);
  const int b = m0 >> 11, s0 = m0 & 2047;   // 128-row tile never crosses a batch
  if (z == 2) {
    #pragma unroll
    for (int j = 0; j < 4; ++j) {
      int n_loc = wc * 64 + j * 16 + col;
      float bb = bias[n0 + n_loc];
      #pragma unroll
      for (int i = 0; i < 4; ++i) {
        int s_loc = wr * 64 + i * 16 + qd * 4;
        half4v h = pack4(acc[i][j][0] + bb, acc[i][j][1] + bb,
                         acc[i][j][2] + bb, acc[i][j][3] + bb);
        *(half4v*)(Es + n_loc * 160 + s_loc) = h;
      }
    }
    __syncthreads();
    #pragma unroll
    for (int it = 0; it < 8; ++it) {
      int row = it * 16 + (tid >> 4);
      int k   = tid & 15;
      half8 vr = *(const half8*)(Es + row * 160 + k * 8);
      *(half8*)(ovt + ((size_t)(b * 768 + n0 + row)) * 2048 + s0 + k * 8) = vr;
    }
  } else {
    _Float16* O = (z == 0) ? oq : ok;
    const float scale = (z == 0) ? LOG2E : 1.0f;
    #pragma unroll
    for (int j = 0; j < 4; ++j) {
      int n_loc = wc * 64 + j * 16 + qd * 4;
      float4 bb = *(const float4*)(bias + n0 + n_loc);
      #pragma unroll
      for (int i = 0; i < 4; ++i) {
        int s_loc = wr * 64 + i * 16 + col;
        half4v h = pack4((acc[i][j][0] + bb.x) * scale, (acc[i][j][1] + bb.y) * scale,
                         (acc[i][j][2] + bb.z) * scale, (acc[i][j][3] + bb.w) * scale);
        *(half4v*)(Es + s_loc * 160 + n_loc) = h;
      }
    }
    __syncthreads();
    const int hh0 = n0 >> 6;
    #pragma unroll
    for (int it = 0; it < 8; ++it) {
      int seg = it * 32 + (tid >> 3);
      int s = seg >> 1, hseg = seg & 1;
      int k = tid & 7;
      half8 vr = *(const half8*)(Es + s * 160 + hseg * 64 + k * 8);
      int mb = (m0 + s) >> 11, sg = (m0 + s) & 2047;
      *(half8*)(O + (size_t)(mb * 12 + hh0 + hseg) * 131072
                  + (size_t)sg * 64 + k * 8) = vr;
    }
  }
}

// ---------------- kernel 3: flash attention -----------------
// r0 structure (256 thr, qt=2, 80 VGPR, 12 waves/CU) + r1's HW-validated
// conflict-free V path:
//  - V reg-staged (global->reg at body top, ds_write_b64 x4 after softmax,
//    T14 async-split) with granule XOR (scg^(d&7)) + half-slot XOR
//    (((d>>3)^d)&1 ^ data-half). r1 measured SQ_LDS_BANK_CONFLICT == 0.
//  - K stays on global_load_lds (was already conflict-free).
//  - exp2 fast path: skip the "-mr" subtract when __all(tile_max <= 0).
//  - staging addresses are incremented pointers, not rebuilt per body.
// qt=4 (r1) spilled (~210 live VGPR vs 128 alloc; WRITE_SIZE 24.6->108 MB) —
// do not widen the wave again without the register budget.

__device__ __forceinline__ void stage_issue(const _Float16* kp, const _Float16* vp,
                                            _Float16* ksd, int4 (&vr)[2], int tid) {
  #pragma unroll
  for (int i = 0; i < 2; ++i)
    gl_lds16(kp + i * 2048, ksd + (i * 256 + tid) * 8);   // K: 64 rows x 128B
  #pragma unroll
  for (int i = 0; i < 2; ++i)
    vr[i] = *(const int4*)(vp + (size_t)i * 65536);       // V^T: rows r0v, r0v+32
}

__device__ __forceinline__ void stage_write(char* vsd, int vwA, int vwB,
                                            const int4 (&vr)[2]) {
  #pragma unroll
  for (int i = 0; i < 2; ++i) {
    int2 lo; lo.x = vr[i].x; lo.y = vr[i].y;
    int2 hi; hi.x = vr[i].z; hi.y = vr[i].w;
    *(int2*)(vsd + vwA + i * 4096) = lo;
    *(int2*)(vsd + vwB + i * 4096) = hi;
  }
}

template <int BUF>
__device__ __forceinline__ void attn_body(
    bool pref, const _Float16*& kp, const _Float16*& vp,
    _Float16* Ks, char* Vs, int tid, int vwA, int vwB,
    const half8 (&qf)[2][2], int kb0, int kb1, const int (&vb)[4],
    float (&nm)[2], floatx4 (&ol)[2], floatx4 (&o)[4][2])
{
  int4 vr[2];
  if (pref) {
    stage_issue(kp, vp, Ks + (1 - BUF) * 4096, vr, tid);
    kp += 4096;   // next 64 j rows of K
    vp += 64;     // next 64 j cols of V^T
  }

  const char* ksb = (const char*)Ks + BUF * 8192;
  const char* vsb = Vs + BUF * 8192;

  half8 kf0[4], kf1[4];
  #pragma unroll
  for (int t = 0; t < 4; ++t) {
    kf0[t] = *(const half8*)(ksb + t * 2048 + kb0);
    kf1[t] = *(const half8*)(ksb + t * 2048 + kb1);
  }

  // QK^T + online softmax (exp2 domain; Q pre-scaled by log2e)
  half4v pf[4][2];
  #pragma unroll
  for (int qt = 0; qt < 2; ++qt) {
    floatx4 seed = {nm[qt], nm[qt], nm[qt], nm[qt]};
    floatx4 st[4];
    #pragma unroll
    for (int t = 0; t < 4; ++t) {
      st[t] = __builtin_amdgcn_mfma_f32_16x16x32_f16(kf0[t], qf[qt][0], seed, 0, 0, 0);
      st[t] = __builtin_amdgcn_mfma_f32_16x16x32_f16(kf1[t], qf[qt][1], st[t], 0, 0, 0);
    }
    float v = fmaxf(
        fmaxf(fmaxf(fmaxf(st[0][0], st[0][1]), fmaxf(st[0][2], st[0][3])),
              fmaxf(fmaxf(st[1][0], st[1][1]), fmaxf(st[1][2], st[1][3]))),
        fmaxf(fmaxf(fmaxf(st[2][0], st[2][1]), fmaxf(st[2][2], st[2][3])),
              fmaxf(fmaxf(st[3][0], st[3][1]), fmaxf(st[3][2], st[3][3]))));
    v = fmaxf(v, __shfl_xor(v, 16, 64));
    v = fmaxf(v, __shfl_xor(v, 32, 64));
    if (__any(v > 0.f)) {            // rare: running max must move
      float mr = fmaxf(v, 0.f);
      float al = __builtin_amdgcn_exp2f(-mr);
      nm[qt] -= mr;
      ol[qt] *= al;
      #pragma unroll
      for (int dt = 0; dt < 4; ++dt) o[dt][qt] *= al;
      #pragma unroll
      for (int t = 0; t < 4; ++t)
        pf[t][qt] = pack4(__builtin_amdgcn_exp2f(st[t][0] - mr),
                          __builtin_amdgcn_exp2f(st[t][1] - mr),
                          __builtin_amdgcn_exp2f(st[t][2] - mr),
                          __builtin_amdgcn_exp2f(st[t][3] - mr));
    } else {                         // common: st <= 0 already
      #pragma unroll
      for (int t = 0; t < 4; ++t)
        pf[t][qt] = pack4(__builtin_amdgcn_exp2f(st[t][0]),
                          __builtin_amdgcn_exp2f(st[t][1]),
                          __builtin_amdgcn_exp2f(st[t][2]),
                          __builtin_amdgcn_exp2f(st[t][3]));
    }
  }

  // V staging writes (loads issued at body top had QK+softmax to land;
  // barrier at end of previous body guarantees 1-BUF is no longer read)
  if (pref)
    stage_write(Vs + (1 - BUF) * 8192, vwA, vwB, vr);

  // PV: out^T = V^T . P (K=16, P straight from regs); ones-row MFMA carries l
  const half4v vone = {(_Float16)1.0f, (_Float16)1.0f, (_Float16)1.0f, (_Float16)1.0f};
  #pragma unroll
  for (int dt = 0; dt < 4; ++dt) {
    #pragma unroll
    for (int t = 0; t < 4; ++t) {
      half4v vf = *(const half4v*)(vsb + dt * 2048 + vb[t]);
      #pragma unroll
      for (int qt = 0; qt < 2; ++qt)
        o[dt][qt] = __builtin_amdgcn_mfma_f32_16x16x16f16(vf, pf[t][qt], o[dt][qt], 0, 0, 0);
    }
  }
  #pragma unroll
  for (int t = 0; t < 4; ++t)
    #pragma unroll
    for (int qt = 0; qt < 2; ++qt)
      ol[qt] = __builtin_amdgcn_mfma_f32_16x16x16f16(vone, pf[t][qt], ol[qt], 0, 0, 0);

  __syncthreads();
}

__global__ __launch_bounds__(256, 3) void attn_kernel(
    const _Float16* __restrict__ Qm,   // [48][2048][64] (log2e-scaled)
    const _Float16* __restrict__ Km,   // [48][2048][64]
    const _Float16* __restrict__ Vt,   // [48][64][2048]
    float* __restrict__ out)           // [4][2048][768]
{
  __shared__ __attribute__((aligned(16))) _Float16 Ks[2 * 4096];  // 16 KB
  __shared__ __attribute__((aligned(16))) char     Vs[2 * 8192];  // 16 KB
  const int bh = blockIdx.x;                 // XCD = bh % 8 (48 % 8 == 0)
  const int q0 = blockIdx.y * 128;
  const int tid = threadIdx.x, lane = tid & 63, w = tid >> 6;
  const int qd = lane >> 4, col = lane & 15, c7 = col & 7;
  const _Float16* Qg = Qm + (size_t)bh * 131072;
  const _Float16* Kg = Km + (size_t)bh * 131072;
  const _Float16* Vg = Vt + (size_t)bh * 131072;

  // Q fragments direct from global (kept in regs for the whole kernel)
  half8 qf[2][2];
  #pragma unroll
  for (int qt = 0; qt < 2; ++qt)
    #pragma unroll
    for (int ks = 0; ks < 2; ++ks)
      qf[qt][ks] = *(const half8*)(Qg + (size_t)(q0 + w * 32 + qt * 16 + col) * 64
                                   + (ks * 4 + qd) * 8);

  // loop-invariant per-lane LDS byte offsets
  const int kb0 = col * 128 + ((qd ^ c7) * 16);
  const int kb1 = col * 128 + (((4 + qd) ^ c7) * 16);
  const int rsz = ((col >> 3) ^ col) & 1;              // read-side half-slot xor
  int vb[4];
  #pragma unroll
  for (int t = 0; t < 4; ++t)
    vb[t] = col * 128 + ((((2 * t) | (qd >> 1)) ^ c7) * 16) + (((qd & 1) ^ rsz) * 8);

  // staging geometry (constant per thread)
  const int r0v = tid >> 3, scg = tid & 7;             // 32 rows x 8 granules
  const int gsw = scg ^ (r0v & 7);
  const int wsz = ((r0v >> 3) ^ r0v) & 1;              // write-side half-slot xor
  const int vwA = r0v * 128 + gsw * 16 + wsz * 8;      // lo half dest
  const int vwB = vwA ^ 8;                             // hi half dest
  const _Float16* kp = Kg + r0v * 64 + gsw * 8;        // pre-swizzled K source
  const _Float16* vp = Vg + (size_t)r0v * 2048 + scg * 8;

  float nm[2] = {100.f, 100.f};      // forces first-tile rescale; flushes o,ol
  const floatx4 z4 = {0.f, 0.f, 0.f, 0.f};
  floatx4 ol[2] = {z4, z4};
  floatx4 o[4][2];
  #pragma unroll
  for (int dt = 0; dt < 4; ++dt)
    #pragma unroll
    for (int qt = 0; qt < 2; ++qt) o[dt][qt] = z4;

  // prologue: stage tile 0 into buf 0
  {
    int4 vr0[2];
    stage_issue(kp, vp, Ks, vr0, tid);
    kp += 4096; vp += 64;
    stage_write(Vs, vwA, vwB, vr0);
  }
  __syncthreads();

  for (int jj = 0; jj < 2048; jj += 128) {
    attn_body<0>(true,            kp, vp, Ks, Vs, tid, vwA, vwB, qf, kb0, kb1, vb, nm, ol, o);
    attn_body<1>(jj + 128 < 2048, kp, vp, Ks, Vs, tid, vwA, vwB, qf, kb0, kb1, vb, nm, ol, o);
  }

  // epilogue: l from the ones-MFMA accumulator (all 4 regs equal, col=q)
  const int b = bh / 12, h = bh % 12;
  #pragma unroll
  for (int qt = 0; qt < 2; ++qt) {
    float inv = 1.0f / ol[qt][0];
    int qg = q0 + w * 32 + qt * 16 + col;
    float* obase = out + ((size_t)b * 2048 + qg) * 768 + h * 64;
    #pragma unroll
    for (int dt = 0; dt < 4; ++dt) {
      floatx4 v = o[dt][qt];
      v *= inv;
      *(floatx4*)(obase + dt * 16 + qd * 4) = v;
    }
  }
}

// ---------------- launcher ----------------
extern "C" void kernel_launch(void* const* d_in, const int* in_sizes, int n_in,
                              void* d_out, int out_size, void* d_ws, size_t ws_size,
                              hipStream_t stream) {
  const float* q  = (const float*)d_in[0];
  const float* k  = (const float*)d_in[1];
  const float* v  = (const float*)d_in[2];
  const float* Wq = (const float*)d_in[3];
  const float* bq = (const float*)d_in[4];
  const float* Wk = (const float*)d_in[5];
  const float* bk = (const float*)d_in[6];
  const float* Wv = (const float*)d_in[7];
  const float* bv = (const float*)d_in[8];

  const size_t NX = 6291456;   // 4*2048*768
  const size_t NW = 589824;    // 768*768
  const size_t need = (3 * NW + 3 * NX) * sizeof(_Float16);
  if (ws_size < need) return;

  _Float16* wh = (_Float16*)d_ws;            // [3][768][768] f16 weights
  _Float16* qh = wh + 3 * NW;                // Q' [48][2048][64] (log2e-scaled)
  _Float16* kh = qh + NX;                    // K' [48][2048][64]
  _Float16* vt = kh + NX;                    // V'^T [48][64][2048]

  CvtArgs ca;
  ca.src[0] = Wq; ca.src[1] = Wk; ca.src[2] = Wv;
  ca.dst[0] = wh; ca.dst[1] = wh + NW; ca.dst[2] = wh + 2 * NW;

  cvt_kernel<<<dim3(288, 3), 256, 0, stream>>>(ca);
  qkv_gemm<<<dim3(64, 6, 3), 256, 0, stream>>>(q, k, v, wh, bq, bk, bv, qh, kh, vt);
  attn_kernel<<<dim3(48, 16), 256, 0, stream>>>(qh, kh, vt, (float*)d_out);
}

// Round 3
// 258.374 us; speedup vs baseline: 1.3402x; 1.0003x over previous
//
#include <hip/hip_runtime.h>
#include <stdint.h>

typedef _Float16 half8  __attribute__((ext_vector_type(8)));
typedef _Float16 half4v __attribute__((ext_vector_type(4)));
typedef float    floatx4 __attribute__((ext_vector_type(4)));

#define LOG2E 1.44269504088896340736f

// async global->LDS 16B copy (LDS dest must be wave-uniform base + lane*16)
__device__ __forceinline__ void gl_lds16(const _Float16* g, _Float16* l) {
  __builtin_amdgcn_global_load_lds(
      (__attribute__((address_space(1))) void*)g,
      (__attribute__((address_space(3))) void*)l, 16, 0, 0);
}
__device__ __forceinline__ void gl_lds16f(const float* g, float* l) {
  __builtin_amdgcn_global_load_lds(
      (__attribute__((address_space(1))) void*)g,
      (__attribute__((address_space(3))) void*)l, 16, 0, 0);
}

__device__ __forceinline__ half4v pack4(float a, float b, float c, float d) {
  auto lo = __builtin_amdgcn_cvt_pkrtz(a, b);
  auto hi = __builtin_amdgcn_cvt_pkrtz(c, d);
  return half4v{static_cast<_Float16>(lo[0]), static_cast<_Float16>(lo[1]),
                static_cast<_Float16>(hi[0]), static_cast<_Float16>(hi[1])};
}
__device__ __forceinline__ half8 cvt8(floatx4 a, floatx4 b) {
  half4v lo = pack4(a[0], a[1], a[2], a[3]);
  half4v hi = pack4(b[0], b[1], b[2], b[3]);
  return __builtin_shufflevector(lo, hi, 0, 1, 2, 3, 4, 5, 6, 7);
}

// ---------------- kernel 1: fp32 -> f16 convert (weights only) ----------------
struct CvtArgs {
  const float* src[3];
  _Float16*    dst[3];
};

__global__ void cvt_kernel(CvtArgs a) {
  const int z = blockIdx.y;
  const int i = (blockIdx.x * 256 + threadIdx.x) * 8;
  const float4* s = (const float4*)(a.src[z] + i);
  float4 v0 = s[0], v1 = s[1];
  half8 h = { (_Float16)v0.x, (_Float16)v0.y, (_Float16)v0.z, (_Float16)v0.w,
              (_Float16)v1.x, (_Float16)v1.y, (_Float16)v1.z, (_Float16)v1.w };
  *(half8*)(a.dst[z] + i) = h;
}

// ---------------- kernel 2: QKV projection GEMM (unchanged this round) -------
__device__ __forceinline__ void gemm_stage(const float* __restrict__ X,
                                           const _Float16* __restrict__ W,
                                           float* Asb, _Float16* Bsb,
                                           int m0, int n0, int k0, int tid) {
  #pragma unroll
  for (int i = 0; i < 4; ++i) {          // A: 128 rows x 32 fp32 = 16KB
    int G = i * 256 + tid;
    int r = G >> 3, gl = G & 7;
    int g = gl ^ (r & 7);
    gl_lds16f(X + (size_t)(m0 + r) * 768 + k0 + g * 4, Asb + G * 4);
  }
  #pragma unroll
  for (int i = 0; i < 2; ++i) {          // B: 128 rows x 32 f16 = 8KB
    int G = i * 256 + tid;
    int r = G >> 2, gl = G & 3;
    int g = gl ^ ((r >> 1) & 3);
    gl_lds16(W + (size_t)(n0 + r) * 768 + k0 + g * 8, Bsb + G * 8);
  }
}

template <int BUF>
__device__ __forceinline__ void gemm_body(
    int knext, const float* __restrict__ X, const _Float16* __restrict__ W,
    float* As, _Float16* Bs, int m0, int n0, int tid, int z,
    int wr, int wc, int qd, int col, floatx4 (&acc)[4][4])
{
  if (knext < 768)
    gemm_stage(X, W, As + (1 - BUF) * 4096, Bs + (1 - BUF) * 4096, m0, n0, knext, tid);

  half8 af[4], bf[4];
  #pragma unroll
  for (int t = 0; t < 4; ++t) {
    int ra = wr * 64 + t * 16 + col;
    const float* Ab = As + BUF * 4096 + ra * 32;
    floatx4 a0 = *(const floatx4*)(Ab + (((2 * qd)     ^ (ra & 7)) * 4));
    floatx4 a1 = *(const floatx4*)(Ab + (((2 * qd + 1) ^ (ra & 7)) * 4));
    af[t] = cvt8(a0, a1);
  }
  #pragma unroll
  for (int t = 0; t < 4; ++t) {
    int rb = wc * 64 + t * 16 + col;
    bf[t] = *(const half8*)(Bs + BUF * 4096 + rb * 32 + ((qd ^ ((rb >> 1) & 3)) * 8));
  }
  if (z == 2) {
    #pragma unroll
    for (int i = 0; i < 4; ++i)
      #pragma unroll
      for (int j = 0; j < 4; ++j)
        acc[i][j] = __builtin_amdgcn_mfma_f32_16x16x32_f16(af[i], bf[j], acc[i][j], 0, 0, 0);
  } else {
    #pragma unroll
    for (int i = 0; i < 4; ++i)
      #pragma unroll
      for (int j = 0; j < 4; ++j)
        acc[i][j] = __builtin_amdgcn_mfma_f32_16x16x32_f16(bf[j], af[i], acc[i][j], 0, 0, 0);
  }
  __syncthreads();
}

__global__ __launch_bounds__(256, 2) void qkv_gemm(
    const float* __restrict__ qx, const float* __restrict__ kx, const float* __restrict__ vx,
    const _Float16* __restrict__ wh,
    const float* __restrict__ bqp, const float* __restrict__ bkp, const float* __restrict__ bvp,
    _Float16* __restrict__ oq, _Float16* __restrict__ ok, _Float16* __restrict__ ovt)
{
  __shared__ __attribute__((aligned(16))) char smem[49152];
  float*    As = (float*)smem;                    // 2*4096 fp32 = 32 KB
  _Float16* Bs = (_Float16*)(smem + 32768);       // 2*4096 f16  = 16 KB
  _Float16* Es = (_Float16*)smem;                 // epilogue 128 rows x 160 halfs = 40 KB

  const int z  = blockIdx.z;
  const float* X = (z == 0) ? qx : ((z == 1) ? kx : vx);
  const _Float16* W = wh + (size_t)z * 589824;
  const int m0 = blockIdx.x * 128, n0 = blockIdx.y * 128;
  const int tid  = threadIdx.x;
  const int lane = tid & 63, wid = tid >> 6;
  const int wr = wid >> 1, wc = wid & 1;
  const int qd = lane >> 4, col = lane & 15;

  const floatx4 z4 = {0.f, 0.f, 0.f, 0.f};
  floatx4 acc[4][4];
  #pragma unroll
  for (int i = 0; i < 4; ++i)
    #pragma unroll
    for (int j = 0; j < 4; ++j) acc[i][j] = z4;

  gemm_stage(X, W, As, Bs, m0, n0, 0, tid);
  __syncthreads();
  for (int kk = 0; kk < 768; kk += 64) {
    gemm_body<0>(kk + 32, X, W, As, Bs, m0, n0, tid, z, wr, wc, qd, col, acc);
    gemm_body<1>(kk + 64, X, W, As, Bs, m0, n0, tid, z, wr, wc, qd, col, acc);
  }
  // last gemm_body ended with __syncthreads: As/Bs dead, Es reusable

  const float* bias = (z == 0) ? bqp : ((z == 1) ? bkp : bvp);
  const int b = m0 >> 11, s0 = m0 & 2047;   // 128-row tile never crosses a batch
  if (z == 2) {
    #pragma unroll
    for (int j = 0; j < 4; ++j) {
      int n_loc = wc * 64 + j * 16 + col;
      float bb = bias[n0 + n_loc];
      #pragma unroll
      for (int i = 0; i < 4; ++i) {
        int s_loc = wr * 64 + i * 16 + qd * 4;
        half4v h = pack4(acc[i][j][0] + bb, acc[i][j][1] + bb,
                         acc[i][j][2] + bb, acc[i][j][3] + bb);
        *(half4v*)(Es + n_loc * 160 + s_loc) = h;
      }
    }
    __syncthreads();
    #pragma unroll
    for (int it = 0; it < 8; ++it) {
      int row = it * 16 + (tid >> 4);
      int k   = tid & 15;
      half8 vr = *(const half8*)(Es + row * 160 + k * 8);
      *(half8*)(ovt + ((size_t)(b * 768 + n0 + row)) * 2048 + s0 + k * 8) = vr;
    }
  } else {
    _Float16* O = (z == 0) ? oq : ok;
    const float scale = (z == 0) ? LOG2E : 1.0f;
    #pragma unroll
    for (int j = 0; j < 4; ++j) {
      int n_loc = wc * 64 + j * 16 + qd * 4;
      float4 bb = *(const float4*)(bias + n0 + n_loc);
      #pragma unroll
      for (int i = 0; i < 4; ++i) {
        int s_loc = wr * 64 + i * 16 + col;
        half4v h = pack4((acc[i][j][0] + bb.x) * scale, (acc[i][j][1] + bb.y) * scale,
                         (acc[i][j][2] + bb.z) * scale, (acc[i][j][3] + bb.w) * scale);
        *(half4v*)(Es + s_loc * 160 + n_loc) = h;
      }
    }
    __syncthreads();
    const int hh0 = n0 >> 6;
    #pragma unroll
    for (int it = 0; it < 8; ++it) {
      int seg = it * 32 + (tid >> 3);
      int s = seg >> 1, hseg = seg & 1;
      int k = tid & 7;
      half8 vr = *(const half8*)(Es + s * 160 + hseg * 64 + k * 8);
      int mb = (m0 + s) >> 11, sg = (m0 + s) & 2047;
      *(half8*)(O + (size_t)(mb * 12 + hh0 + hseg) * 131072
                  + (size_t)sg * 64 + k * 8) = vr;
    }
  }
}

// ---------------- kernel 3: flash attention -----------------
// r0<->r2 A/B: V bank conflicts (6.29M cyc) were NOT on the critical path
// (removing them via reg-staging cost +5us). Data paths here = r0 exactly
// (K AND V via global_load_lds, same swizzles). The structural change is
// T3/T4: 3 LDS buffers, 2-deep prefetch, raw s_barrier + counted
// s_waitcnt vmcnt(4) at body entry (never a full vmcnt(0) drain in the
// steady-state loop — hipcc's __syncthreads forced one per body).
//   body t: wait vmcnt(4)  [tile t's 4 loads = oldest; t+1's may fly]
//           s_barrier; sched_barrier(0)            [rule #18 fence]
//           stage tile t+2 -> buf (t+2)%3          [4 gl_lds/thread]
//           compute tile t from buf t%3
// Tail: t=30 vmcnt(4), t=31 vmcnt(0) (derivation in session notes).
// Also: T5 setprio around MFMA clusters (attn-proven +4-7%), exp2
// fast path (skip "-mr" when __all(tile_max<=0)).

__device__ __forceinline__ void stage_kv(const _Float16* __restrict__ Kg,
                                         const _Float16* __restrict__ Vg,
                                         _Float16* ksd, _Float16* vsd, int j0, int tid) {
  #pragma unroll
  for (int i = 0; i < 2; ++i) {
    int c = i * 256 + tid;
    int row = c >> 3, sc = c & 7;
    gl_lds16(Kg + (size_t)(j0 + row) * 64 + ((sc ^ (row & 7)) * 8), ksd + c * 8);
    gl_lds16(Vg + (size_t)row * 2048 + j0 + ((sc ^ (row & 7)) * 8), vsd + c * 8);
  }
}

__device__ __forceinline__ void attn_half(
    const char* ksb, const char* vsb,
    const half8 (&qf)[2][2], int kb0, int kb1, const int (&vb)[4],
    float (&nm)[2], floatx4 (&ol)[2], floatx4 (&o)[4][2])
{
  half8 kf0[4], kf1[4];
  #pragma unroll
  for (int t = 0; t < 4; ++t) {
    kf0[t] = *(const half8*)(ksb + t * 2048 + kb0);
    kf1[t] = *(const half8*)(ksb + t * 2048 + kb1);
  }

  // QK^T + online softmax (exp2 domain; Q pre-scaled by log2e)
  half4v pf[4][2];
  #pragma unroll
  for (int qt = 0; qt < 2; ++qt) {
    floatx4 seed = {nm[qt], nm[qt], nm[qt], nm[qt]};
    floatx4 st[4];
    __builtin_amdgcn_s_setprio(1);
    #pragma unroll
    for (int t = 0; t < 4; ++t) {
      st[t] = __builtin_amdgcn_mfma_f32_16x16x32_f16(kf0[t], qf[qt][0], seed, 0, 0, 0);
      st[t] = __builtin_amdgcn_mfma_f32_16x16x32_f16(kf1[t], qf[qt][1], st[t], 0, 0, 0);
    }
    __builtin_amdgcn_s_setprio(0);
    float v = fmaxf(
        fmaxf(fmaxf(fmaxf(st[0][0], st[0][1]), fmaxf(st[0][2], st[0][3])),
              fmaxf(fmaxf(st[1][0], st[1][1]), fmaxf(st[1][2], st[1][3]))),
        fmaxf(fmaxf(fmaxf(st[2][0], st[2][1]), fmaxf(st[2][2], st[2][3])),
              fmaxf(fmaxf(st[3][0], st[3][1]), fmaxf(st[3][2], st[3][3]))));
    v = fmaxf(v, __shfl_xor(v, 16, 64));
    v = fmaxf(v, __shfl_xor(v, 32, 64));
    if (__any(v > 0.f)) {            // rare: running max must move
      float mr = fmaxf(v, 0.f);
      float al = __builtin_amdgcn_exp2f(-mr);
      nm[qt] -= mr;
      ol[qt] *= al;
      #pragma unroll
      for (int dt = 0; dt < 4; ++dt) o[dt][qt] *= al;
      #pragma unroll
      for (int t = 0; t < 4; ++t)
        pf[t][qt] = pack4(__builtin_amdgcn_exp2f(st[t][0] - mr),
                          __builtin_amdgcn_exp2f(st[t][1] - mr),
                          __builtin_amdgcn_exp2f(st[t][2] - mr),
                          __builtin_amdgcn_exp2f(st[t][3] - mr));
    } else {                         // common: st <= 0 already
      #pragma unroll
      for (int t = 0; t < 4; ++t)
        pf[t][qt] = pack4(__builtin_amdgcn_exp2f(st[t][0]),
                          __builtin_amdgcn_exp2f(st[t][1]),
                          __builtin_amdgcn_exp2f(st[t][2]),
                          __builtin_amdgcn_exp2f(st[t][3]));
    }
  }

  // PV: out^T = V^T . P (K=16, P straight from regs); ones-row MFMA carries l
  const half4v vone = {(_Float16)1.0f, (_Float16)1.0f, (_Float16)1.0f, (_Float16)1.0f};
  __builtin_amdgcn_s_setprio(1);
  #pragma unroll
  for (int dt = 0; dt < 4; ++dt) {
    #pragma unroll
    for (int t = 0; t < 4; ++t) {
      half4v vf = *(const half4v*)(vsb + dt * 2048 + vb[t]);
      #pragma unroll
      for (int qt = 0; qt < 2; ++qt)
        o[dt][qt] = __builtin_amdgcn_mfma_f32_16x16x16f16(vf, pf[t][qt], o[dt][qt], 0, 0, 0);
    }
  }
  #pragma unroll
  for (int t = 0; t < 4; ++t)
    #pragma unroll
    for (int qt = 0; qt < 2; ++qt)
      ol[qt] = __builtin_amdgcn_mfma_f32_16x16x16f16(vone, pf[t][qt], ol[qt], 0, 0, 0);
  __builtin_amdgcn_s_setprio(0);
}

template <int RB, int WB, int VM>
__device__ __forceinline__ void attn_body(
    bool pref, int jn, const _Float16* __restrict__ Kg, const _Float16* __restrict__ Vg,
    _Float16* Ks, _Float16* Vs, int tid,
    const half8 (&qf)[2][2], int kb0, int kb1, const int (&vb)[4],
    float (&nm)[2], floatx4 (&ol)[2], floatx4 (&o)[4][2])
{
  asm volatile("s_waitcnt vmcnt(%0)" :: "i"(VM) : "memory");
  __builtin_amdgcn_s_barrier();
  __builtin_amdgcn_sched_barrier(0);
  if (pref)
    stage_kv(Kg, Vg, Ks + WB * 4096, Vs + WB * 4096, jn, tid);
  __builtin_amdgcn_sched_barrier(0);
  attn_half((const char*)(Ks + RB * 4096), (const char*)(Vs + RB * 4096),
            qf, kb0, kb1, vb, nm, ol, o);
}

__global__ __launch_bounds__(256, 3) void attn_kernel(
    const _Float16* __restrict__ Qm,   // [48][2048][64] (log2e-scaled)
    const _Float16* __restrict__ Km,   // [48][2048][64]
    const _Float16* __restrict__ Vt,   // [48][64][2048]
    float* __restrict__ out)           // [4][2048][768]
{
  __shared__ __attribute__((aligned(16))) _Float16 Ks[3 * 4096];  // 24 KB
  __shared__ __attribute__((aligned(16))) _Float16 Vs[3 * 4096];  // 24 KB
  const int bh = blockIdx.x;                 // XCD = bh % 8 (48 % 8 == 0)
  const int q0 = blockIdx.y * 128;
  const int tid = threadIdx.x, lane = tid & 63, w = tid >> 6;
  const int qd = lane >> 4, col = lane & 15, c7 = col & 7;
  const _Float16* Qg = Qm + (size_t)bh * 131072;
  const _Float16* Kg = Km + (size_t)bh * 131072;
  const _Float16* Vg = Vt + (size_t)bh * 131072;

  // Q fragments direct from global (kept in regs for the whole kernel)
  half8 qf[2][2];
  #pragma unroll
  for (int qt = 0; qt < 2; ++qt)
    #pragma unroll
    for (int ks = 0; ks < 2; ++ks)
      qf[qt][ks] = *(const half8*)(Qg + (size_t)(q0 + w * 32 + qt * 16 + col) * 64
                                   + (ks * 4 + qd) * 8);

  // loop-invariant per-lane LDS byte offsets (r0 layout)
  const int kb0 = col * 128 + ((qd ^ c7) * 16);
  const int kb1 = col * 128 + (((4 + qd) ^ c7) * 16);
  const int vq = (qd >> 1) ^ c7;
  int vb[4];
  #pragma unroll
  for (int t = 0; t < 4; ++t)
    vb[t] = col * 128 + (qd & 1) * 8 + ((vq ^ (2 * t)) * 16);

  float nm[2] = {100.f, 100.f};      // forces first-tile rescale; flushes o,ol
  const floatx4 z4 = {0.f, 0.f, 0.f, 0.f};
  floatx4 ol[2] = {z4, z4};
  floatx4 o[4][2];
  #pragma unroll
  for (int dt = 0; dt < 4; ++dt)
    #pragma unroll
    for (int qt = 0; qt < 2; ++qt) o[dt][qt] = z4;

  // prologue: stage tiles 0 and 1 into bufs 0 and 1 (8 gl_lds/thread)
  stage_kv(Kg, Vg, Ks,        Vs,        0,  tid);
  stage_kv(Kg, Vg, Ks + 4096, Vs + 4096, 64, tid);

  int jn = 128;
  #pragma unroll 1
  for (int it = 0; it < 10; ++it) {   // bodies t = 3*it .. 3*it+2
    attn_body<0, 2, 4>(true, jn,       Kg, Vg, Ks, Vs, tid, qf, kb0, kb1, vb, nm, ol, o);
    attn_body<1, 0, 4>(true, jn + 64,  Kg, Vg, Ks, Vs, tid, qf, kb0, kb1, vb, nm, ol, o);
    attn_body<2, 1, 4>(true, jn + 128, Kg, Vg, Ks, Vs, tid, qf, kb0, kb1, vb, nm, ol, o);
    jn += 192;
  }
  // tail: t = 30 (reads buf 0; tile 31's 4 loads may still fly), t = 31
  attn_body<0, 2, 4>(false, 0, Kg, Vg, Ks, Vs, tid, qf, kb0, kb1, vb, nm, ol, o);
  attn_body<1, 0, 0>(false, 0, Kg, Vg, Ks, Vs, tid, qf, kb0, kb1, vb, nm, ol, o);

  // epilogue: l from the ones-MFMA accumulator (all 4 regs equal, col=q)
  const int b = bh / 12, h = bh % 12;
  #pragma unroll
  for (int qt = 0; qt < 2; ++qt) {
    float inv = 1.0f / ol[qt][0];
    int qg = q0 + w * 32 + qt * 16 + col;
    float* obase = out + ((size_t)b * 2048 + qg) * 768 + h * 64;
    #pragma unroll
    for (int dt = 0; dt < 4; ++dt) {
      floatx4 v = o[dt][qt];
      v *= inv;
      *(floatx4*)(obase + dt * 16 + qd * 4) = v;
    }
  }
}

// ---------------- launcher ----------------
extern "C" void kernel_launch(void* const* d_in, const int* in_sizes, int n_in,
                              void* d_out, int out_size, void* d_ws, size_t ws_size,
                              hipStream_t stream) {
  const float* q  = (const float*)d_in[0];
  const float* k  = (const float*)d_in[1];
  const float* v  = (const float*)d_in[2];
  const float* Wq = (const float*)d_in[3];
  const float* bq = (const float*)d_in[4];
  const float* Wk = (const float*)d_in[5];
  const float* bk = (const float*)d_in[6];
  const float* Wv = (const float*)d_in[7];
  const float* bv = (const float*)d_in[8];

  const size_t NX = 6291456;   // 4*2048*768
  const size_t NW = 589824;    // 768*768
  const size_t need = (3 * NW + 3 * NX) * sizeof(_Float16);
  if (ws_size < need) return;

  _Float16* wh = (_Float16*)d_ws;            // [3][768][768] f16 weights
  _Float16* qh = wh + 3 * NW;                // Q' [48][2048][64] (log2e-scaled)
  _Float16* kh = qh + NX;                    // K' [48][2048][64]
  _Float16* vt = kh + NX;                    // V'^T [48][64][2048]

  CvtArgs ca;
  ca.src[0] = Wq; ca.src[1] = Wk; ca.src[2] = Wv;
  ca.dst[0] = wh; ca.dst[1] = wh + NW; ca.dst[2] = wh + 2 * NW;

  cvt_kernel<<<dim3(288, 3), 256, 0, stream>>>(ca);
  qkv_gemm<<<dim3(64, 6, 3), 256, 0, stream>>>(q, k, v, wh, bq, bk, bv, qh, kh, vt);
  attn_kernel<<<dim3(48, 16), 256, 0, stream>>>(qh, kh, vt, (float*)d_out);
}